// Round 7
// baseline (611.866 us; speedup 1.0000x reference)
//
#include <hip/hip_runtime.h>
#include <hip/hip_bf16.h>
#include <cstdint>

#define T_STEPS 250
#define BATCH   256
#define NI      700
#define NH      1024
#define NO      20
#define BETAF   0.9f
#define KPAD    704          // 22 * 32
#define KT_N    22
#define KCAT    2112         // 3 * KPAD

typedef __attribute__((ext_vector_type(8))) short bf16x8;
typedef __attribute__((ext_vector_type(4))) float f32x4;

static __device__ __forceinline__ unsigned short f2bu(float x) {
    union { __hip_bfloat16 h; unsigned short u; } c;
    c.h = __float2bfloat16(x);
    return c.u;
}
static __device__ __forceinline__ float b2f(unsigned short u) {
    union { __hip_bfloat16 h; unsigned short u; } c;
    c.u = u;
    return __bfloat162float(c.h);
}

// ---------------------------------------------------------------------------
// K0: zero LIF state; W2T[h][o]; Bcat = [hi|mid|lo] bf16 split of W1,
//     padded K 700->704. 3-split = 27 mantissa bits -> exact vs fp32.
// ---------------------------------------------------------------------------
__global__ __launch_bounds__(256) void k0_init(const float* __restrict__ W1,
                                               const float* __restrict__ W2,
                                               float* __restrict__ W2T,
                                               float* __restrict__ mem1,
                                               unsigned short* __restrict__ Bcat) {
    int idx = blockIdx.x * 256 + threadIdx.x;
    if (idx < BATCH * NH) mem1[idx] = 0.f;
    if (idx < NH * NO) {
        int h = idx / NO, o = idx % NO;
        W2T[idx] = W2[o * NH + h];
    }
    if (idx < NH * KPAD) {
        int n = idx / KPAD, k = idx % KPAD;
        float w = (k < NI) ? W1[n * NI + k] : 0.f;
        unsigned short hu = f2bu(w);
        float r1 = w - b2f(hu);
        unsigned short mu = f2bu(r1);
        float r2 = r1 - b2f(mu);
        unsigned short lu = f2bu(r2);
        unsigned short* row = Bcat + (size_t)n * KCAT + k;
        row[0]        = hu;
        row[KPAD]     = mu;
        row[2 * KPAD] = lu;
    }
}

// ---------------------------------------------------------------------------
// K2: fc1 via bf16 MFMA, 3-way B split, R4-PROVEN single-buffer 2-barrier
//   structure (269us / MfmaUtil 46 / 0 conflicts), with A staged as RAW
//   FP32 SPIKES via global_load_lds (k1 fused away; cvt 0/1->bf16 exact in
//   regs after ds_read -> cur1 bit-identical to R4).
//   LDS 40KB: Asf fp32 [128][32] (16KB) + Bs bf16 [3][128][32] (24KB).
//   Swizzles (linear dest + pre-swizzled per-lane SOURCE, swizzled read):
//     A (8 chunks/row, 128B rows): phys chunk p holds logical p ^ (row&7)
//       -> frag reads spread evenly, 8 lanes/16B slot = BW floor.
//     B (4 chunks/row,  64B rows): phys p holds logical p ^ ((row>>1)&3)
//       -> R4-proven, counter = 0.
//   XCD-grouped bid swizzle: 8 n-tiles of one m-panel per XCD (A panel
//   read once per XCD, L2-shared by its 8 blocks).
// ---------------------------------------------------------------------------
__global__ __launch_bounds__(256) void k2_fc1(const float* __restrict__ A,
                                              const unsigned short* __restrict__ Bcat,
                                              float* __restrict__ C) {
    __shared__ float          Asf[128 * 32];
    __shared__ unsigned short Bs[3][128 * 32];
    const int tid  = threadIdx.x;
    const int lane = tid & 63;
    const int wv   = tid >> 6;

    int nwg = gridDim.x, bid = blockIdx.x, w;
    if ((nwg & 7) == 0) w = (bid & 7) * (nwg >> 3) + (bid >> 3);
    else                w = bid;
    const int brow = (w >> 3) * 128;
    const int bn   = (w & 7) * 128;
    const int wm   = (wv >> 1) * 64;
    const int wn   = (wv & 1) * 64;

    f32x4 acc[4][4];
#pragma unroll
    for (int i = 0; i < 4; ++i)
#pragma unroll
        for (int j = 0; j < 4; ++j) acc[i][j] = (f32x4){0.f, 0.f, 0.f, 0.f};

    // ---- A staging: 1024 16B chunks (4/thread), fp32 source, linear dest.
    auto stageA = [&](int kt) {
#pragma unroll
        for (int j = 0; j < 4; ++j) {
            int c   = wv * 256 + j * 64 + lane;
            int row = c >> 3;
            int lk  = (c & 7) ^ (row & 7);           // logical chunk for this slot
            int srck = kt * 32 + lk * 4;
            const float* src = A + (size_t)(brow + row) * NI + srck;
            if (srck >= NI) src = A + (size_t)(brow + row) * NI;  // finite x B-pad(0)
            __builtin_amdgcn_global_load_lds(
                (const __attribute__((address_space(1))) void*)src,
                (__attribute__((address_space(3))) void*)(Asf + (wv * 256 + j * 64) * 4),
                16, 0, 0);
        }
    };
    // ---- B staging: 1536 16B chunks (6/thread), bf16 source, linear dest.
    const unsigned short* Bb = Bcat + (size_t)bn * KCAT;
    auto stageB = [&](int kt) {
#pragma unroll
        for (int s = 0; s < 3; ++s)
#pragma unroll
            for (int j = 0; j < 2; ++j) {
                int c   = wv * 128 + j * 64 + lane;
                int row = c >> 2;
                int lk  = ((c & 3) ^ ((row >> 1) & 3)) * 8;
                const unsigned short* src = Bb + (size_t)row * KCAT + s * KPAD + kt * 32 + lk;
                __builtin_amdgcn_global_load_lds(
                    (const __attribute__((address_space(1))) void*)src,
                    (__attribute__((address_space(3))) void*)(Bs[s] + (wv * 128 + j * 64) * 8),
                    16, 0, 0);
            }
    };

    const int frow = lane & 15;
    const int fsl  = (((lane >> 4) & 3) ^ ((frow >> 1) & 3)) * 8;  // B frag slot (elems)
    const int ac   = (lane >> 4) * 2;                              // A logical chunk pair

    for (int kt = 0; kt < KT_N; ++kt) {
        stageA(kt);
        stageB(kt);
        __syncthreads();   // vmcnt(0) drain: tiles ready

        bf16x8 a[4];
#pragma unroll
        for (int i = 0; i < 4; ++i) {
            int row = wm + i * 16 + frow;
            int p0  = (ac)     ^ (row & 7);
            int p1  = (ac + 1) ^ (row & 7);
            float4 va = *(const float4*)&Asf[row * 32 + p0 * 4];
            float4 vb = *(const float4*)&Asf[row * 32 + p1 * 4];
            bf16x8 t;
            t[0] = (short)f2bu(va.x); t[1] = (short)f2bu(va.y);
            t[2] = (short)f2bu(va.z); t[3] = (short)f2bu(va.w);
            t[4] = (short)f2bu(vb.x); t[5] = (short)f2bu(vb.y);
            t[6] = (short)f2bu(vb.z); t[7] = (short)f2bu(vb.w);
            a[i] = t;
        }
#pragma unroll
        for (int s = 0; s < 3; ++s) {
#pragma unroll
            for (int j = 0; j < 4; ++j) {
                bf16x8 b = *(const bf16x8*)&Bs[s][(wn + j * 16 + frow) * 32 + fsl];
#pragma unroll
                for (int i = 0; i < 4; ++i)
                    acc[i][j] = __builtin_amdgcn_mfma_f32_16x16x32_bf16(a[i], b, acc[i][j], 0, 0, 0);
            }
        }
        __syncthreads();   // reads done before next overwrite
    }

    // C/D layout: col = lane&15, row = (lane>>4)*4 + q
#pragma unroll
    for (int i = 0; i < 4; ++i) {
#pragma unroll
        for (int j = 0; j < 4; ++j) {
            int col  = bn + wn + j * 16 + (lane & 15);
            int row0 = brow + wm + i * 16 + ((lane >> 4) << 2);
#pragma unroll
            for (int q = 0; q < 4; ++q)
                C[(size_t)(row0 + q) * NH + col] = acc[i][j][q];
        }
    }
}

// ---------------------------------------------------------------------------
// K3: LIF scan, 4-deep explicit prefetch (named regs, static indexing).
// ---------------------------------------------------------------------------
__global__ __launch_bounds__(256) void k3_lif(const float* __restrict__ cur1,
                                              float* __restrict__ mem1,
                                              unsigned long long* __restrict__ bits,
                                              int TC) {
    int b = blockIdx.x >> 2;
    int hg = blockIdx.x & 3;
    int h = hg * 256 + threadIdx.x;
    const size_t S = (size_t)BATCH * NH;
    const float* p = cur1 + (size_t)b * NH + h;
    unsigned long long* bp = bits + (size_t)b * 16 + hg * 4 + (threadIdx.x >> 6);
    const bool lead = (threadIdx.x & 63) == 0;
    float mem = mem1[b * NH + h];

#define LIF_STEP(cv, t)                                                        \
    {                                                                          \
        float reset = (mem > 1.0f) ? 1.0f : 0.0f;                              \
        mem = fmaf(BETAF, mem, (cv)) - reset;                                  \
        unsigned long long mk = __ballot(mem > 1.0f);                          \
        if (lead) bp[(size_t)(t) * (BATCH * 16)] = mk;                         \
    }

    float c0 = (0 < TC) ? p[0] : 0.f;
    float c1 = (1 < TC) ? p[S] : 0.f;
    float c2 = (2 < TC) ? p[2 * S] : 0.f;
    float c3 = (3 < TC) ? p[3 * S] : 0.f;
    int tc = 0;
    for (; tc + 4 <= TC; tc += 4) {
        LIF_STEP(c0, tc + 0); if (tc + 4 < TC) c0 = p[(size_t)(tc + 4) * S];
        LIF_STEP(c1, tc + 1); if (tc + 5 < TC) c1 = p[(size_t)(tc + 5) * S];
        LIF_STEP(c2, tc + 2); if (tc + 6 < TC) c2 = p[(size_t)(tc + 6) * S];
        LIF_STEP(c3, tc + 3); if (tc + 7 < TC) c3 = p[(size_t)(tc + 7) * S];
    }
    for (; tc < TC; ++tc) { float c = p[(size_t)tc * S]; LIF_STEP(c, tc); }
#undef LIF_STEP
    mem1[b * NH + h] = mem;
}

// ---------------------------------------------------------------------------
// K4: fc2 sparse gather, WAVE-PARALLEL: one block per (t,b) row, each of
//     4 waves handles 4 of the 16 mask words (2-wide dual chains -> 8
//     independent L2 loads in flight per block), LDS combine.
// ---------------------------------------------------------------------------
__global__ __launch_bounds__(256) void k4_fc2(const unsigned long long* __restrict__ bits,
                                              const float* __restrict__ W2T,
                                              float* __restrict__ cur2) {
    __shared__ float part[4][NO];
    int row  = blockIdx.x;
    int wv   = threadIdx.x >> 6;
    int lane = threadIdx.x & 63;
    bool act = lane < NO;
    unsigned long long mv = (lane < 4) ? bits[(size_t)row * 16 + wv * 4 + lane] : 0ULL;
    const float* W = W2T + (act ? lane : 0);
    float p0 = 0.f, p1 = 0.f;
#pragma unroll
    for (int i = 0; i < 4; ++i) {
        unsigned long long m = __shfl(mv, i);
        int base = (wv * 4 + i) * 64;
        while (m) {
            int  b0 = __ffsll(m) - 1;            m &= m - 1;
            bool v1 = m != 0;
            int  b1 = v1 ? __ffsll(m) - 1 : 0;   m &= m - 1;
            float w0 = W[(base + b0) * NO];
            float w1 = W[(base + b1) * NO];
            p0 += w0;
            p1 += v1 ? w1 : 0.f;
        }
    }
    float p = p0 + p1;
    if (wv != 0 && act) part[wv][lane] = p;
    __syncthreads();
    if (wv == 0 && act) {
        p += part[1][lane] + part[2][lane] + part[3][lane];
        cur2[(size_t)row * NO + lane] = p;
    }
}

// ---------------------------------------------------------------------------
// K5: leaky readout + softmax (no max-subtract; |mem| bounded), prefetch.
// ---------------------------------------------------------------------------
__global__ __launch_bounds__(256) void k5_readout(const float* __restrict__ cur2,
                                                  float* __restrict__ out_mem,
                                                  float* __restrict__ out_sm) {
    int b = blockIdx.x * 8 + (threadIdx.x >> 5);
    int o = threadIdx.x & 31;
    bool act = o < NO;
    const float* p = cur2 + (size_t)b * NO + (act ? o : 0);
    float mem = 0.f;
    float nxt = p[0];
    for (int t = 0; t < T_STEPS; ++t) {
        float c = nxt;
        if (t + 1 < T_STEPS) nxt = p[(size_t)(t + 1) * BATCH * NO];
        mem = fmaf(BETAF, mem, c);
        float e = act ? __expf(mem) : 0.f;
        float s = e;
#pragma unroll
        for (int off = 16; off; off >>= 1) s += __shfl_xor(s, off, 32);
        if (act) {
            int base = (t * BATCH + b) * NO;
            out_mem[base + o] = mem;
            out_sm[base + o] = __fdividef(e, s);
        }
    }
}

// ---------------------------------------------------------------------------
extern "C" void kernel_launch(void* const* d_in, const int* in_sizes, int n_in,
                              void* d_out, int out_size, void* d_ws, size_t ws_size,
                              hipStream_t stream) {
    const float* spikes = (const float*)d_in[0];   // [250,256,700]
    const float* W1     = (const float*)d_in[1];   // [1024,700]
    const float* W2     = (const float*)d_in[2];   // [20,1024]
    float* out_mem = (float*)d_out;                              // [250,256,20]
    float* out_sm  = out_mem + (size_t)T_STEPS * BATCH * NO;     // [250,256,20]

    char* ws = (char*)d_ws;
    size_t off = 0;
    auto alloc = [&](size_t bytes) -> char* {
        off = (off + 255) & ~(size_t)255;
        char* p = ws + off;
        off += bytes;
        return p;
    };
    float*          W2T  = (float*)alloc((size_t)NH * NO * 4);
    float*          mem1 = (float*)alloc((size_t)BATCH * NH * 4);
    float*          cur2 = (float*)alloc((size_t)T_STEPS * BATCH * NO * 4);
    unsigned short* Bcat = (unsigned short*)alloc((size_t)NH * KCAT * 2);

    // T-chunking: per step need cur1 (1 MB) + bits (32 KB).
    size_t fixed = (off + 255) & ~(size_t)255;
    size_t rem = ws_size > fixed ? ws_size - fixed : 0;
    size_t per_t = (size_t)BATCH * NH * 4 + (size_t)BATCH * 16 * 8 + 512;
    int TC = (int)(rem / per_t);
    if (TC > T_STEPS) TC = T_STEPS;
    if (TC < 1) TC = 1;
    float*              cur1 = (float*)alloc((size_t)TC * BATCH * NH * 4);
    unsigned long long* bits = (unsigned long long*)alloc((size_t)TC * BATCH * 16 * 8);

    k0_init<<<(NH * KPAD + 255) / 256, 256, 0, stream>>>(W1, W2, W2T, mem1, Bcat);

    for (int t0 = 0; t0 < T_STEPS; t0 += TC) {
        int tc = T_STEPS - t0 < TC ? T_STEPS - t0 : TC;
        int rows = tc * BATCH;
        int nwg = (rows / 128) * 8;
        k2_fc1<<<nwg, 256, 0, stream>>>(spikes + (size_t)t0 * BATCH * NI, Bcat, cur1);
        k3_lif<<<1024, 256, 0, stream>>>(cur1, mem1, bits, tc);
        k4_fc2<<<rows, 256, 0, stream>>>(bits, W2T, cur2 + (size_t)t0 * BATCH * NO);
    }

    k5_readout<<<32, 256, 0, stream>>>(cur2, out_mem, out_sm);
}

// Round 8
// 603.891 us; speedup vs baseline: 1.0132x; 1.0132x over previous
//
#include <hip/hip_runtime.h>
#include <hip/hip_bf16.h>
#include <cstdint>

#define T_STEPS 250
#define BATCH   256
#define NI      700
#define NH      1024
#define NO      20
#define BETAF   0.9f
#define KPAD    704          // 22 * 32
#define KCAT    2112         // 3 * KPAD (K-extension: C = [A A A]·[Bhi;Bmid;Blo])
#define NKT     66           // 2112 / 32 K-ext steps

typedef __attribute__((ext_vector_type(8))) short bf16x8;
typedef __attribute__((ext_vector_type(4))) float f32x4;

static __device__ __forceinline__ unsigned short f2bu(float x) {
    union { __hip_bfloat16 h; unsigned short u; } c;
    c.h = __float2bfloat16(x);
    return c.u;
}
static __device__ __forceinline__ float b2f(unsigned short u) {
    union { __hip_bfloat16 h; unsigned short u; } c;
    c.u = u;
    return __bfloat162float(c.h);
}

// ---------------------------------------------------------------------------
// K0: zero LIF state; W2T[h][o]; Bcat = [hi|mid|lo] bf16 split of W1,
//     padded K 700->704. 3-split = 27 mantissa bits -> exact vs fp32.
// ---------------------------------------------------------------------------
__global__ __launch_bounds__(256) void k0_init(const float* __restrict__ W1,
                                               const float* __restrict__ W2,
                                               float* __restrict__ W2T,
                                               float* __restrict__ mem1,
                                               unsigned short* __restrict__ Bcat) {
    int idx = blockIdx.x * 256 + threadIdx.x;
    if (idx < BATCH * NH) mem1[idx] = 0.f;
    if (idx < NH * NO) {
        int h = idx / NO, o = idx % NO;
        W2T[idx] = W2[o * NH + h];
    }
    if (idx < NH * KPAD) {
        int n = idx / KPAD, k = idx % KPAD;
        float w = (k < NI) ? W1[n * NI + k] : 0.f;
        unsigned short hu = f2bu(w);
        float r1 = w - b2f(hu);
        unsigned short mu = f2bu(r1);
        float r2 = r1 - b2f(mu);
        unsigned short lu = f2bu(r2);
        unsigned short* row = Bcat + (size_t)n * KCAT + k;
        row[0]        = hu;
        row[KPAD]     = mu;
        row[2 * KPAD] = lu;
    }
}

// ---------------------------------------------------------------------------
// K1: convert fp32 binary spikes [rows][700] -> bf16 [rows][704] (exact).
// ---------------------------------------------------------------------------
__global__ __launch_bounds__(256) void k1_cvt(const float* __restrict__ A,
                                              unsigned short* __restrict__ Abf,
                                              int rows) {
    int idx = blockIdx.x * 256 + threadIdx.x;   // quad index: 176 per row
    int r = idx / 176, q = idx - r * 176;
    if (r >= rows) return;
    int k = q * 4;
    ushort4 o = make_ushort4(0, 0, 0, 0);
    if (k < NI) {
        float4 v = *(const float4*)(A + (size_t)r * NI + k);
        o.x = f2bu(v.x); o.y = f2bu(v.y); o.z = f2bu(v.z); o.w = f2bu(v.w);
    }
    *(ushort4*)(Abf + (size_t)r * KPAD + k) = o;
}

// ---------------------------------------------------------------------------
// K2: fc1 bf16 MFMA GEMM over K_ext = 2112 (3-split folded into K).
//   Per K-step: one 128x32 A-tile (col = kt*32 mod 704) + one 128x32 B-tile
//   (col = kt*32 in Bcat), 16 MFMA. Double-buffered 2x16KB = 32 KB LDS
//   (R4 occupancy preserved). T3+T4 schedule — counted vmcnt, raw barriers:
//     stage(kt+1 -> buf^1); s_waitcnt vmcnt(4); s_barrier;
//     ds_read+MFMA on buf; s_barrier
//   The 4 in-flight next-tile loads cross the barrier (never drained to 0
//   in the loop). Write-after-read safe: each wave's ds_reads drain via
//   MFMA data-deps before its trailing barrier; stage writes happen after.
//   LDS swizzle (R4-proven, 0 conflicts): phys 16B chunk p of row r holds
//   logical chunk p ^ ((r>>1)&3); linear gload_lds dest + pre-swizzled
//   per-lane source; swizzled frag read. XCD-grouped bid swizzle.
// ---------------------------------------------------------------------------
__global__ __launch_bounds__(256) void k2_fc1(const unsigned short* __restrict__ Abf,
                                              const unsigned short* __restrict__ Bcat,
                                              float* __restrict__ C) {
    __shared__ unsigned short As[2][128 * 32];
    __shared__ unsigned short Bs[2][128 * 32];
    const int tid  = threadIdx.x;
    const int lane = tid & 63;
    const int wv   = tid >> 6;

    int nwg = gridDim.x, bid = blockIdx.x, w;
    if ((nwg & 7) == 0) w = (bid & 7) * (nwg >> 3) + (bid >> 3);
    else                w = bid;
    const int brow = (w >> 3) * 128;
    const int bn   = (w & 7) * 128;
    const int wm   = (wv >> 1) * 64;
    const int wn   = (wv & 1) * 64;

    f32x4 acc[4][4];
#pragma unroll
    for (int i = 0; i < 4; ++i)
#pragma unroll
        for (int j = 0; j < 4; ++j) acc[i][j] = (f32x4){0.f, 0.f, 0.f, 0.f};

    // stage one 128x32 bf16 tile: 512 16B chunks, 2 gload_lds per thread;
    // linear LDS dest (wave base + lane*16), per-lane pre-swizzled source.
    auto stage = [&](const unsigned short* gbase, int rstride, int kcol,
                     unsigned short* lds) {
#pragma unroll
        for (int j = 0; j < 2; ++j) {
            int c   = wv * 128 + j * 64 + lane;
            int row = c >> 2;
            int lk  = ((c & 3) ^ ((row >> 1) & 3)) * 8;
            const unsigned short* src = gbase + (size_t)row * rstride + kcol + lk;
            __builtin_amdgcn_global_load_lds(
                (const __attribute__((address_space(1))) void*)src,
                (__attribute__((address_space(3))) void*)(lds + (wv * 128 + j * 64) * 8),
                16, 0, 0);
        }
    };

    const unsigned short* Ab = Abf + (size_t)brow * KPAD;
    const unsigned short* Bb = Bcat + (size_t)bn * KCAT;

    const int frow = lane & 15;
    const int fsl  = (((lane >> 4) & 3) ^ ((frow >> 1) & 3)) * 8;

    auto compute = [&](int cur) {
        const unsigned short* Ac = As[cur];
        const unsigned short* Bc = Bs[cur];
        bf16x8 a[4];
#pragma unroll
        for (int i = 0; i < 4; ++i)
            a[i] = *(const bf16x8*)&Ac[(wm + i * 16 + frow) * 32 + fsl];
        __builtin_amdgcn_s_setprio(1);
#pragma unroll
        for (int j = 0; j < 4; ++j) {
            bf16x8 b = *(const bf16x8*)&Bc[(wn + j * 16 + frow) * 32 + fsl];
#pragma unroll
            for (int i = 0; i < 4; ++i)
                acc[i][j] = __builtin_amdgcn_mfma_f32_16x16x32_bf16(a[i], b, acc[i][j], 0, 0, 0);
        }
        __builtin_amdgcn_s_setprio(0);
    };

    // prologue: stage tile 0
    stage(Ab, KPAD, 0, As[0]);
    stage(Bb, KCAT, 0, Bs[0]);

    int akn = 32;   // A column of tile kt+1 (kt*32 mod 704)
    for (int kt = 0; kt < NKT - 1; ++kt) {
        const int cur = kt & 1;
        stage(Ab, KPAD, akn, As[cur ^ 1]);
        stage(Bb, KCAT, (kt + 1) * 32, Bs[cur ^ 1]);
        akn += 32; if (akn == KPAD) akn = 0;

        asm volatile("s_waitcnt vmcnt(4)" ::: "memory");  // tile kt landed; kt+1 in flight
        __builtin_amdgcn_s_barrier();
        __builtin_amdgcn_sched_barrier(0);
        compute(cur);
        __builtin_amdgcn_s_barrier();                     // reads done before next overwrite
        __builtin_amdgcn_sched_barrier(0);
    }
    asm volatile("s_waitcnt vmcnt(0)" ::: "memory");      // last tile
    __builtin_amdgcn_s_barrier();
    __builtin_amdgcn_sched_barrier(0);
    compute((NKT - 1) & 1);

    // C/D layout: col = lane&15, row = (lane>>4)*4 + q
#pragma unroll
    for (int i = 0; i < 4; ++i) {
#pragma unroll
        for (int j = 0; j < 4; ++j) {
            int col  = bn + wn + j * 16 + (lane & 15);
            int row0 = brow + wm + i * 16 + ((lane >> 4) << 2);
#pragma unroll
            for (int q = 0; q < 4; ++q)
                C[(size_t)(row0 + q) * NH + col] = acc[i][j][q];
        }
    }
}

// ---------------------------------------------------------------------------
// K3: LIF scan, 4-deep explicit prefetch (named regs, static indexing).
// ---------------------------------------------------------------------------
__global__ __launch_bounds__(256) void k3_lif(const float* __restrict__ cur1,
                                              float* __restrict__ mem1,
                                              unsigned long long* __restrict__ bits,
                                              int TC) {
    int b = blockIdx.x >> 2;
    int hg = blockIdx.x & 3;
    int h = hg * 256 + threadIdx.x;
    const size_t S = (size_t)BATCH * NH;
    const float* p = cur1 + (size_t)b * NH + h;
    unsigned long long* bp = bits + (size_t)b * 16 + hg * 4 + (threadIdx.x >> 6);
    const bool lead = (threadIdx.x & 63) == 0;
    float mem = mem1[b * NH + h];

#define LIF_STEP(cv, t)                                                        \
    {                                                                          \
        float reset = (mem > 1.0f) ? 1.0f : 0.0f;                              \
        mem = fmaf(BETAF, mem, (cv)) - reset;                                  \
        unsigned long long mk = __ballot(mem > 1.0f);                          \
        if (lead) bp[(size_t)(t) * (BATCH * 16)] = mk;                         \
    }

    float c0 = (0 < TC) ? p[0] : 0.f;
    float c1 = (1 < TC) ? p[S] : 0.f;
    float c2 = (2 < TC) ? p[2 * S] : 0.f;
    float c3 = (3 < TC) ? p[3 * S] : 0.f;
    int tc = 0;
    for (; tc + 4 <= TC; tc += 4) {
        LIF_STEP(c0, tc + 0); if (tc + 4 < TC) c0 = p[(size_t)(tc + 4) * S];
        LIF_STEP(c1, tc + 1); if (tc + 5 < TC) c1 = p[(size_t)(tc + 5) * S];
        LIF_STEP(c2, tc + 2); if (tc + 6 < TC) c2 = p[(size_t)(tc + 6) * S];
        LIF_STEP(c3, tc + 3); if (tc + 7 < TC) c3 = p[(size_t)(tc + 7) * S];
    }
    for (; tc < TC; ++tc) { float c = p[(size_t)tc * S]; LIF_STEP(c, tc); }
#undef LIF_STEP
    mem1[b * NH + h] = mem;
}

// ---------------------------------------------------------------------------
// K4: fc2 sparse gather, wave-parallel: one block per (t,b) row, 4 waves x
//     4 mask words each, 2-wide dual chains, LDS combine.
// ---------------------------------------------------------------------------
__global__ __launch_bounds__(256) void k4_fc2(const unsigned long long* __restrict__ bits,
                                              const float* __restrict__ W2T,
                                              float* __restrict__ cur2) {
    __shared__ float part[4][NO];
    int row  = blockIdx.x;
    int wv   = threadIdx.x >> 6;
    int lane = threadIdx.x & 63;
    bool act = lane < NO;
    unsigned long long mv = (lane < 4) ? bits[(size_t)row * 16 + wv * 4 + lane] : 0ULL;
    const float* W = W2T + (act ? lane : 0);
    float p0 = 0.f, p1 = 0.f;
#pragma unroll
    for (int i = 0; i < 4; ++i) {
        unsigned long long m = __shfl(mv, i);
        int base = (wv * 4 + i) * 64;
        while (m) {
            int  b0 = __ffsll(m) - 1;            m &= m - 1;
            bool v1 = m != 0;
            int  b1 = v1 ? __ffsll(m) - 1 : 0;   m &= m - 1;
            float w0 = W[(base + b0) * NO];
            float w1 = W[(base + b1) * NO];
            p0 += w0;
            p1 += v1 ? w1 : 0.f;
        }
    }
    float p = p0 + p1;
    if (wv != 0 && act) part[wv][lane] = p;
    __syncthreads();
    if (wv == 0 && act) {
        p += part[1][lane] + part[2][lane] + part[3][lane];
        cur2[(size_t)row * NO + lane] = p;
    }
}

// ---------------------------------------------------------------------------
// K5: leaky readout + softmax (no max-subtract; |mem| bounded), prefetch.
// ---------------------------------------------------------------------------
__global__ __launch_bounds__(256) void k5_readout(const float* __restrict__ cur2,
                                                  float* __restrict__ out_mem,
                                                  float* __restrict__ out_sm) {
    int b = blockIdx.x * 8 + (threadIdx.x >> 5);
    int o = threadIdx.x & 31;
    bool act = o < NO;
    const float* p = cur2 + (size_t)b * NO + (act ? o : 0);
    float mem = 0.f;
    float nxt = p[0];
    for (int t = 0; t < T_STEPS; ++t) {
        float c = nxt;
        if (t + 1 < T_STEPS) nxt = p[(size_t)(t + 1) * BATCH * NO];
        mem = fmaf(BETAF, mem, c);
        float e = act ? __expf(mem) : 0.f;
        float s = e;
#pragma unroll
        for (int off = 16; off; off >>= 1) s += __shfl_xor(s, off, 32);
        if (act) {
            int base = (t * BATCH + b) * NO;
            out_mem[base + o] = mem;
            out_sm[base + o] = __fdividef(e, s);
        }
    }
}

// ---------------------------------------------------------------------------
extern "C" void kernel_launch(void* const* d_in, const int* in_sizes, int n_in,
                              void* d_out, int out_size, void* d_ws, size_t ws_size,
                              hipStream_t stream) {
    const float* spikes = (const float*)d_in[0];   // [250,256,700]
    const float* W1     = (const float*)d_in[1];   // [1024,700]
    const float* W2     = (const float*)d_in[2];   // [20,1024]
    float* out_mem = (float*)d_out;                              // [250,256,20]
    float* out_sm  = out_mem + (size_t)T_STEPS * BATCH * NO;     // [250,256,20]

    char* ws = (char*)d_ws;
    size_t off = 0;
    auto alloc = [&](size_t bytes) -> char* {
        off = (off + 255) & ~(size_t)255;
        char* p = ws + off;
        off += bytes;
        return p;
    };
    float*          W2T  = (float*)alloc((size_t)NH * NO * 4);
    float*          mem1 = (float*)alloc((size_t)BATCH * NH * 4);
    float*          cur2 = (float*)alloc((size_t)T_STEPS * BATCH * NO * 4);
    unsigned short* Bcat = (unsigned short*)alloc((size_t)NH * KCAT * 2);

    // T-chunking: per step need cur1 (1 MB) + Abf (352 KB) + bits (32 KB).
    size_t fixed = (off + 255) & ~(size_t)255;
    size_t rem = ws_size > fixed ? ws_size - fixed : 0;
    size_t per_t = (size_t)BATCH * NH * 4 + (size_t)BATCH * KPAD * 2
                 + (size_t)BATCH * 16 * 8 + 768;
    int TC = (int)(rem / per_t);
    if (TC > T_STEPS) TC = T_STEPS;
    if (TC < 1) TC = 1;
    float*              cur1 = (float*)alloc((size_t)TC * BATCH * NH * 4);
    unsigned short*     Abf  = (unsigned short*)alloc((size_t)TC * BATCH * KPAD * 2);
    unsigned long long* bits = (unsigned long long*)alloc((size_t)TC * BATCH * 16 * 8);

    k0_init<<<(NH * KPAD + 255) / 256, 256, 0, stream>>>(W1, W2, W2T, mem1, Bcat);

    for (int t0 = 0; t0 < T_STEPS; t0 += TC) {
        int tc = T_STEPS - t0 < TC ? T_STEPS - t0 : TC;
        int rows = tc * BATCH;
        k1_cvt<<<(rows * 176 + 255) / 256, 256, 0, stream>>>(
            spikes + (size_t)t0 * BATCH * NI, Abf, rows);
        int nwg = (rows / 128) * 8;
        k2_fc1<<<nwg, 256, 0, stream>>>(Abf, Bcat, cur1);
        k3_lif<<<1024, 256, 0, stream>>>(cur1, mem1, bits, tc);
        k4_fc2<<<rows, 256, 0, stream>>>(bits, W2T, cur2 + (size_t)t0 * BATCH * NO);
    }

    k5_readout<<<32, 256, 0, stream>>>(cur2, out_mem, out_sm);
}